// Round 1
// baseline (18949.570 us; speedup 1.0000x reference)
//
#include <hip/hip_runtime.h>

#define BLOCK 256
#define NF 8      // node features
#define NE 32     // embed dim
#define NI 40     // F + E, MLP input
#define NH 64     // hidden

#define FMA4(acc, s, w)                       \
    {                                         \
        acc.x = fmaf((s), (w).x, acc.x);      \
        acc.y = fmaf((s), (w).y, acc.y);      \
        acc.z = fmaf((s), (w).z, acc.z);      \
        acc.w = fmaf((s), (w).w, acc.w);      \
    }

__global__ __launch_bounds__(BLOCK) void dag_mlp_seg(
    const float* __restrict__ x, const float* __restrict__ h_node,
    const float* __restrict__ W1, const float* __restrict__ b1,
    const float* __restrict__ W2, const float* __restrict__ b2,
    const float* __restrict__ W3, const float* __restrict__ b3,
    const int* __restrict__ ptr, float* __restrict__ out,
    int n, int m)
{
    // Weights staged in LDS once per block (35.5 KB; re-reads hit L1/L2 since
    // the working set is tiny). Broadcast reads (all lanes same addr) are
    // conflict-free.
    __shared__ __align__(16) float sW1[NI * NH];
    __shared__ __align__(16) float sW2[NH * NH];
    __shared__ __align__(16) float sW3[NH * NE];
    __shared__ __align__(16) float sB1[NH];
    __shared__ __align__(16) float sB2[NH];
    __shared__ __align__(16) float sB3[NE];

    const int tid = threadIdx.x;
    for (int i = tid; i < NI * NH; i += BLOCK) sW1[i] = W1[i];
    for (int i = tid; i < NH * NH; i += BLOCK) sW2[i] = W2[i];
    for (int i = tid; i < NH * NE; i += BLOCK) sW3[i] = W3[i];
    if (tid < NH) { sB1[tid] = b1[tid]; sB2[tid] = b2[tid]; }
    if (tid < NE) sB3[tid] = b3[tid];
    __syncthreads();

    const int node = blockIdx.x * BLOCK + tid;
    const bool valid = node < n;

    // ---- load inputs (concat [x | h_node]) ----
    float in[NI];
    if (valid) {
        const float4* xp = reinterpret_cast<const float4*>(x + (size_t)node * NF);
        float4 a0 = xp[0], a1 = xp[1];
        in[0] = a0.x; in[1] = a0.y; in[2] = a0.z; in[3] = a0.w;
        in[4] = a1.x; in[5] = a1.y; in[6] = a1.z; in[7] = a1.w;
        const float4* hp = reinterpret_cast<const float4*>(h_node + (size_t)node * NE);
#pragma unroll
        for (int q = 0; q < 8; ++q) {
            float4 v = hp[q];
            in[NF + 4 * q + 0] = v.x;
            in[NF + 4 * q + 1] = v.y;
            in[NF + 4 * q + 2] = v.z;
            in[NF + 4 * q + 3] = v.w;
        }
    } else {
#pragma unroll
        for (int k = 0; k < NI; ++k) in[k] = 0.f;
    }

    // ---- layer 1: [40] -> [64], ReLU ----
    float h1v[NH];
#pragma unroll
    for (int jc = 0; jc < NH; jc += 4) {
        float4 acc = *reinterpret_cast<const float4*>(&sB1[jc]);
#pragma unroll
        for (int k = 0; k < NI; ++k) {
            float4 w = *reinterpret_cast<const float4*>(&sW1[k * NH + jc]);
            FMA4(acc, in[k], w);
        }
        h1v[jc + 0] = fmaxf(acc.x, 0.f);
        h1v[jc + 1] = fmaxf(acc.y, 0.f);
        h1v[jc + 2] = fmaxf(acc.z, 0.f);
        h1v[jc + 3] = fmaxf(acc.w, 0.f);
    }

    // ---- layer 2: [64] -> [64], ReLU ----
    float h2v[NH];
#pragma unroll
    for (int jc = 0; jc < NH; jc += 4) {
        float4 acc = *reinterpret_cast<const float4*>(&sB2[jc]);
#pragma unroll
        for (int k = 0; k < NH; ++k) {
            float4 w = *reinterpret_cast<const float4*>(&sW2[k * NH + jc]);
            FMA4(acc, h1v[k], w);
        }
        h2v[jc + 0] = fmaxf(acc.x, 0.f);
        h2v[jc + 1] = fmaxf(acc.y, 0.f);
        h2v[jc + 2] = fmaxf(acc.z, 0.f);
        h2v[jc + 3] = fmaxf(acc.w, 0.f);
    }

    // ---- layer 3: [64] -> [32], no activation ----
    float ov[NE];
#pragma unroll
    for (int jc = 0; jc < NE; jc += 4) {
        float4 acc = *reinterpret_cast<const float4*>(&sB3[jc]);
#pragma unroll
        for (int k = 0; k < NH; ++k) {
            float4 w = *reinterpret_cast<const float4*>(&sW3[k * NE + jc]);
            FMA4(acc, h2v[k], w);
        }
        ov[jc + 0] = acc.x;
        ov[jc + 1] = acc.y;
        ov[jc + 2] = acc.z;
        ov[jc + 3] = acc.w;
    }

    // ---- segment id: largest s with ptr[s] <= node (CSR semantics incl.
    // empty segments, since then ptr[s] <= node < ptr[s+1]) ----
    int seg = -1;
    if (valid) {
        int lo = 0, hi = m;   // ptr[lo] <= node < ptr[hi]
        while (hi - lo > 1) {
            int mid = (lo + hi) >> 1;
            if (ptr[mid] <= node) lo = mid; else hi = mid;
        }
        seg = lo;
    }

    // ---- wave-level segmented reduction ----
    // Nodes are contiguous along lanes -> seg is non-decreasing per wave.
    // Suffix run-sum via shfl_down doubling; run-head lane atomics once per
    // (wave, segment-run). Invalid lanes carry seg=-1 (own run, never written).
    const int lane = tid & 63;
    const int segUp = __shfl_up(seg, 1);
    const bool head = (lane == 0) || (segUp != seg);

    bool take[6];
#pragma unroll
    for (int i = 0; i < 6; ++i) {
        const int d = 1 << i;
        const int s2 = __shfl_down(seg, d);
        take[i] = (lane + d < 64) && (s2 == seg);
    }

#pragma unroll
    for (int j = 0; j < NE; ++j) {
        float v = valid ? ov[j] : 0.f;
#pragma unroll
        for (int i = 0; i < 6; ++i) {
            const float w = __shfl_down(v, 1 << i);
            if (take[i]) v += w;
        }
        if (head && seg >= 0) {
            atomicAdd(&out[(size_t)seg * NE + j], v);
        }
    }
}

extern "C" void kernel_launch(void* const* d_in, const int* in_sizes, int n_in,
                              void* d_out, int out_size, void* d_ws, size_t ws_size,
                              hipStream_t stream) {
    const float* x      = (const float*)d_in[0];
    const float* h_node = (const float*)d_in[1];
    const float* W1     = (const float*)d_in[2];
    const float* b1     = (const float*)d_in[3];
    const float* W2     = (const float*)d_in[4];
    const float* b2     = (const float*)d_in[5];
    const float* W3     = (const float*)d_in[6];
    const float* b3     = (const float*)d_in[7];
    const int*   ptr    = (const int*)d_in[8];
    float* out = (float*)d_out;

    const int n = in_sizes[0] / NF;   // 2,000,000 nodes
    const int m = out_size / NE;      // 20,000 segments

    // Harness re-poisons d_out with 0xAA before every timed launch; we
    // accumulate with atomics, so zero it first (async memset is
    // graph-capture legal).
    hipMemsetAsync(d_out, 0, (size_t)out_size * sizeof(float), stream);

    const int nb = (n + BLOCK - 1) / BLOCK;
    dag_mlp_seg<<<nb, BLOCK, 0, stream>>>(x, h_node, W1, b1, W2, b2, W3, b3,
                                          ptr, out, n, m);
}

// Round 2
// 823.045 us; speedup vs baseline: 23.0237x; 23.0237x over previous
//
#include <hip/hip_runtime.h>

#define BLOCK 256
#define NPB 64          // nodes per block (one per lane; 4 waves split columns)
#define NF 8            // node features
#define NE 32           // embed dim
#define NI 40           // F + E
#define NH 64           // hidden
#define LDSW 65         // LDS row stride (65 -> lane=node access is conflict-free)

typedef float fvec16 __attribute__((ext_vector_type(16)));
typedef float fvec8  __attribute__((ext_vector_type(8)));

__global__ __launch_bounds__(BLOCK, 4) void dag_mlp_seg(
    const float* __restrict__ x, const float* __restrict__ h_node,
    const float* __restrict__ W1, const float* __restrict__ b1,
    const float* __restrict__ W2, const float* __restrict__ b2,
    const float* __restrict__ W3, const float* __restrict__ b3,
    const int* __restrict__ ptr, float* __restrict__ out,
    int n, int m)
{
    // sA: inputs (rows of 40), later reused for H2 (rows of 64).
    // sB: H1 (rows of 64).  2 x 16.6 KB = 33.3 KB -> 4 blocks/CU.
    __shared__ float sA[NPB * LDSW];
    __shared__ float sB[NPB * LDSW];

    const int tid = threadIdx.x;
    const int nd  = tid & 63;                                   // node-in-block = lane
    // wave id; readfirstlane makes it provably uniform so weight-row loads
    // become s_load_dwordx16 (SGPRs), not per-lane vector loads.
    const int g   = __builtin_amdgcn_readfirstlane(tid >> 6);   // 0..3
    const long long node0 = (long long)blockIdx.x * NPB;

    // ---- stage inputs into sA rows: [x(8) | h_node(32)] ----
    {
        // x: 64 nodes * 8 floats = 128 float4
        const long long x4max  = ((long long)n * NF) / 4 - 1;
        const long long h4max  = ((long long)n * NE) / 4 - 1;
        if (tid < 128) {
            long long gi = node0 * (NF / 4) + tid;
            if (gi > x4max) gi = x4max;          // tail clamp (outputs guarded later)
            float4 v = reinterpret_cast<const float4*>(x)[gi];
            const int nd2 = tid >> 1, c = (tid & 1) * 4;
            float* p = &sA[nd2 * LDSW + c];
            p[0] = v.x; p[1] = v.y; p[2] = v.z; p[3] = v.w;
        }
        // h_node: 64 nodes * 32 floats = 512 float4, 2 per thread
#pragma unroll
        for (int r = 0; r < 2; ++r) {
            const int j = tid + r * BLOCK;       // 0..511
            long long gi = node0 * (NE / 4) + j;
            if (gi > h4max) gi = h4max;
            float4 v = reinterpret_cast<const float4*>(h_node)[gi];
            const int nd2 = j >> 3, c = (j & 7) * 4;
            float* p = &sA[nd2 * LDSW + NF + c];
            p[0] = v.x; p[1] = v.y; p[2] = v.z; p[3] = v.w;
        }
    }
    __syncthreads();

    // ---- layer 1: [40] -> [64], this wave computes cols g*16..g*16+15 ----
    float acc[16];
    {
        fvec16 bv = *reinterpret_cast<const fvec16*>(b1 + g * 16);
#pragma unroll
        for (int c = 0; c < 16; ++c) acc[c] = bv[c];
        const float* inRow = &sA[nd * LDSW];
#pragma unroll 8
        for (int k = 0; k < NI; ++k) {
            const float s = inRow[k];                                   // ds_read_b32
            fvec16 w = *reinterpret_cast<const fvec16*>(W1 + k * NH + g * 16); // s_load x16
#pragma unroll
            for (int c = 0; c < 16; ++c) acc[c] = fmaf(s, w[c], acc[c]);
        }
        float* o = &sB[nd * LDSW + g * 16];
#pragma unroll
        for (int c = 0; c < 16; ++c) o[c] = fmaxf(acc[c], 0.f);
    }
    __syncthreads();

    // ---- layer 2: [64] -> [64], reads sB (H1), writes sA (H2) ----
    {
        fvec16 bv = *reinterpret_cast<const fvec16*>(b2 + g * 16);
#pragma unroll
        for (int c = 0; c < 16; ++c) acc[c] = bv[c];
        const float* inRow = &sB[nd * LDSW];
#pragma unroll 8
        for (int k = 0; k < NH; ++k) {
            const float s = inRow[k];
            fvec16 w = *reinterpret_cast<const fvec16*>(W2 + k * NH + g * 16);
#pragma unroll
            for (int c = 0; c < 16; ++c) acc[c] = fmaf(s, w[c], acc[c]);
        }
        float* o = &sA[nd * LDSW + g * 16];
#pragma unroll
        for (int c = 0; c < 16; ++c) o[c] = fmaxf(acc[c], 0.f);
    }
    __syncthreads();

    // ---- layer 3: [64] -> [32], this wave computes cols g*8..g*8+7 ----
    float ov[8];
    {
        fvec8 bv = *reinterpret_cast<const fvec8*>(b3 + g * 8);
#pragma unroll
        for (int c = 0; c < 8; ++c) ov[c] = bv[c];
        const float* inRow = &sA[nd * LDSW];
#pragma unroll 8
        for (int k = 0; k < NH; ++k) {
            const float s = inRow[k];
            fvec8 w = *reinterpret_cast<const fvec8*>(W3 + k * NE + g * 8);
#pragma unroll
            for (int c = 0; c < 8; ++c) ov[c] = fmaf(s, w[c], ov[c]);
        }
    }

    // ---- segment id: largest seg with ptr[seg] <= node ----
    const long long node = node0 + nd;
    const bool valid = node < n;
    int seg = -1;
    if (valid) {
        int lo = 0, hi = m;
        while (hi - lo > 1) {
            int mid = (lo + hi) >> 1;
            if (ptr[mid] <= (int)node) lo = mid; else hi = mid;
        }
        seg = lo;
    }

    // ---- wave-level segmented suffix reduction; lanes = consecutive nodes ----
    const int lane = nd;
    const int segUp = __shfl_up(seg, 1);
    const bool head = (lane == 0) || (segUp != seg);

    bool take[6];
#pragma unroll
    for (int i = 0; i < 6; ++i) {
        const int d = 1 << i;
        const int s2 = __shfl_down(seg, d);
        take[i] = (lane + d < 64) && (s2 == seg);
    }

#pragma unroll
    for (int j = 0; j < 8; ++j) {
        float v = valid ? ov[j] : 0.f;
#pragma unroll
        for (int i = 0; i < 6; ++i) {
            const float w = __shfl_down(v, 1 << i);
            if (take[i]) v += w;
        }
        if (head && seg >= 0) {
            atomicAdd(&out[(size_t)seg * NE + g * 8 + j], v);
        }
    }
}

extern "C" void kernel_launch(void* const* d_in, const int* in_sizes, int n_in,
                              void* d_out, int out_size, void* d_ws, size_t ws_size,
                              hipStream_t stream) {
    const float* x      = (const float*)d_in[0];
    const float* h_node = (const float*)d_in[1];
    const float* W1     = (const float*)d_in[2];
    const float* b1     = (const float*)d_in[3];
    const float* W2     = (const float*)d_in[4];
    const float* b2     = (const float*)d_in[5];
    const float* W3     = (const float*)d_in[6];
    const float* b3     = (const float*)d_in[7];
    const int*   ptr    = (const int*)d_in[8];
    float* out = (float*)d_out;

    const int n = in_sizes[0] / NF;   // 2,000,000 nodes
    const int m = out_size / NE;      // 20,000 segments

    // out is accumulated with atomics; harness poisons it with 0xAA.
    hipMemsetAsync(d_out, 0, (size_t)out_size * sizeof(float), stream);

    const int nb = (n + NPB - 1) / NPB;
    dag_mlp_seg<<<nb, BLOCK, 0, stream>>>(x, h_node, W1, b1, W2, b2, W3, b3,
                                          ptr, out, n, m);
}